// Round 1
// baseline (420.367 us; speedup 1.0000x reference)
//
#include <hip/hip_runtime.h>

// VQ codebook: z_e (262144, 64) f32, embeddings (512, 64) f32.
// Outputs (flat f32 in d_out): z_q_st [N*D], indices-as-float [N], loss [1].

static constexpr int N_TOK = 262144;
static constexpr int K     = 512;
static constexpr int D     = 64;
static constexpr int BLK   = 256;
static constexpr int NBLK  = N_TOK / BLK;  // 1024

// ---- kernel 0: esq[k] = ||e_k||^2 ------------------------------------------
__global__ void esq_kernel(const float* __restrict__ emb, float* __restrict__ esq) {
  int k = threadIdx.x;
  if (k < K) {
    const float4* row = reinterpret_cast<const float4*>(emb + (size_t)k * D);
    float s = 0.f;
#pragma unroll
    for (int i = 0; i < D / 4; ++i) {
      float4 v = row[i];
      s = fmaf(v.x, v.x, s);
      s = fmaf(v.y, v.y, s);
      s = fmaf(v.z, v.z, s);
      s = fmaf(v.w, v.w, s);
    }
    esq[k] = s;
  }
}

// ---- kernel 1: per-token argmin + gather + partial loss --------------------
__global__ __launch_bounds__(BLK) void vq_main(
    const float* __restrict__ z_e, const float* __restrict__ emb,
    const float* __restrict__ esq, float* __restrict__ out_zq,
    float* __restrict__ out_idx, float* __restrict__ block_loss) {
  const int n = blockIdx.x * BLK + threadIdx.x;

  // Token row into registers (16 x float4).
  float z[D];
  {
    const float4* zr = reinterpret_cast<const float4*>(z_e + (size_t)n * D);
#pragma unroll
    for (int i = 0; i < D / 4; ++i) {
      float4 v = zr[i];
      z[4 * i + 0] = v.x; z[4 * i + 1] = v.y;
      z[4 * i + 2] = v.z; z[4 * i + 3] = v.w;
    }
  }

  float best = 3.402823466e38f;
  int   bidx = 0;

  // 4 codes at a time: 4 independent FMA chains (hide dependent-FMA latency).
  // emb/esq accesses are wave-uniform -> expect s_load + SGPR-operand v_fma.
  for (int k0 = 0; k0 < K; k0 += 4) {
    const float* e0 = emb + (size_t)k0 * D;
    float a0 = 0.f, a1 = 0.f, a2 = 0.f, a3 = 0.f;
#pragma unroll
    for (int d = 0; d < D; ++d) {
      float zd = z[d];
      a0 = fmaf(zd, e0[0 * D + d], a0);
      a1 = fmaf(zd, e0[1 * D + d], a1);
      a2 = fmaf(zd, e0[2 * D + d], a2);
      a3 = fmaf(zd, e0[3 * D + d], a3);
    }
    float s0 = fmaf(-2.f, a0, esq[k0 + 0]);
    float s1 = fmaf(-2.f, a1, esq[k0 + 1]);
    float s2 = fmaf(-2.f, a2, esq[k0 + 2]);
    float s3 = fmaf(-2.f, a3, esq[k0 + 3]);
    // Ascending-k strict < keeps jnp.argmin first-min tie semantics.
    if (s0 < best) { best = s0; bidx = k0 + 0; }
    if (s1 < best) { best = s1; bidx = k0 + 1; }
    if (s2 < best) { best = s2; bidx = k0 + 2; }
    if (s3 < best) { best = s3; bidx = k0 + 3; }
  }

  // Gather chosen code, write z_q_st = z + (q - z), accumulate (q - z)^2.
  float lsum = 0.f;
  {
    const float4* er = reinterpret_cast<const float4*>(emb + (size_t)bidx * D);
    float4* orow = reinterpret_cast<float4*>(out_zq + (size_t)n * D);
#pragma unroll
    for (int i = 0; i < D / 4; ++i) {
      float4 q = er[i];
      float zx = z[4 * i + 0], zy = z[4 * i + 1];
      float zz = z[4 * i + 2], zw = z[4 * i + 3];
      float dx = q.x - zx, dy = q.y - zy, dz = q.z - zz, dw = q.w - zw;
      float4 st;
      st.x = zx + dx; st.y = zy + dy; st.z = zz + dz; st.w = zw + dw;
      orow[i] = st;
      lsum = fmaf(dx, dx, lsum);
      lsum = fmaf(dy, dy, lsum);
      lsum = fmaf(dz, dz, lsum);
      lsum = fmaf(dw, dw, lsum);
    }
  }

  out_idx[n] = (float)bidx;

  // Deterministic per-block loss reduction.
  __shared__ float red[BLK];
  red[threadIdx.x] = lsum;
  __syncthreads();
#pragma unroll
  for (int off = BLK / 2; off > 0; off >>= 1) {
    if (threadIdx.x < off) red[threadIdx.x] += red[threadIdx.x + off];
    __syncthreads();
  }
  if (threadIdx.x == 0) block_loss[blockIdx.x] = red[0];
}

// ---- kernel 2: finalize loss (deterministic tree) --------------------------
__global__ __launch_bounds__(BLK) void loss_finalize(
    const float* __restrict__ bl, float* __restrict__ out_loss) {
  __shared__ float sm[BLK];
  float s = 0.f;
  for (int i = threadIdx.x; i < NBLK; i += BLK) s += bl[i];
  sm[threadIdx.x] = s;
  __syncthreads();
#pragma unroll
  for (int off = BLK / 2; off > 0; off >>= 1) {
    if (threadIdx.x < off) sm[threadIdx.x] += sm[threadIdx.x + off];
    __syncthreads();
  }
  if (threadIdx.x == 0) out_loss[0] = sm[0] * (1.0f / 16777216.0f);  // / (N*D)
}

extern "C" void kernel_launch(void* const* d_in, const int* in_sizes, int n_in,
                              void* d_out, int out_size, void* d_ws, size_t ws_size,
                              hipStream_t stream) {
  const float* z_e = (const float*)d_in[0];
  const float* emb = (const float*)d_in[1];

  float* out      = (float*)d_out;
  float* out_zq   = out;                          // N*D
  float* out_idx  = out + (size_t)N_TOK * D;      // N
  float* out_loss = out_idx + N_TOK;              // 1

  float* esq = (float*)d_ws;       // K floats
  float* bl  = esq + K;            // NBLK floats

  esq_kernel<<<1, K, 0, stream>>>(emb, esq);
  vq_main<<<NBLK, BLK, 0, stream>>>(z_e, emb, esq, out_zq, out_idx, bl);
  loss_finalize<<<1, BLK, 0, stream>>>(bl, out_loss);
}